// Round 7
// baseline (5229.074 us; speedup 1.0000x reference)
//
#include <hip/hip_runtime.h>
#include <math.h>

typedef _Float16 f16;
typedef _Float16 f16x8 __attribute__((ext_vector_type(8)));
typedef float f32x4 __attribute__((ext_vector_type(4)));

#define NB 16      // batch
#define NT 16      // time steps
#define NH 64
#define NW 64
#define NF 64      // features
#define NG 256     // 4*F
#define HWF ((size_t)NH * NW * NF)          // 262144
#define OUT_BSTRIDE ((size_t)NT * HWF)      // d_out batch stride
#define RS 16896                            // LDS row stride = 66 * 256 B (x-padded)
#define ZS 258                              // zbuf row stride in floats
#define WSTEP ((size_t)36864)               // per-step wf2 size in f16x8 chunks
#define FSTRIDE 16                          // ints per flag slot (64B)

#define MFMA(a, b, c) __builtin_amdgcn_mfma_f32_16x16x32_f16((a), (b), (c), 0, 0, 0)

__device__ __forceinline__ void gload_lds16(const void* g, void* l) {
    __builtin_amdgcn_global_load_lds(
        (const __attribute__((address_space(1))) unsigned int*)(g),
        (__attribute__((address_space(3))) unsigned int*)(l), 16, 0, 0);
}

__device__ __forceinline__ float hsig(float x) {
    return fminf(fmaxf(0.2f * x + 0.5f, 0.0f), 1.0f);
}

// ---- prologue 0: zero the neighbor-sync flags (every launch — determinism)
__global__ void zero_flags(int* __restrict__ flags) {
    flags[blockIdx.x * 256 + threadIdx.x] = 0;   // NT*512*FSTRIDE ints
}

// ---- prologue 1: fuse W+U, split fp16 hi/lo, lane-ordered chunks:
// chunk (f16x8 units): (tap*2+kk)*2048 + term*1024 + (cout>>4)*64 + lane
// lane = lg*16 + (cout&15) holds cin = kk*32 + lg*8 .. +7.
__global__ void fuse_split_w(const float* __restrict__ k, const float* __restrict__ rk,
                             f16* __restrict__ wf2) {
    int idx = blockIdx.x * 256 + threadIdx.x;      // over 16*9*256*8 = 294912
    if (idx >= NT * 9 * NG * 8) return;
    int g8   = idx & 7;
    int cout = (idx >> 3) & 255;
    int tt   = idx >> 11;          // t*9 + tap
    int tap  = tt % 9;
    int t    = tt / 9;
    int kk = g8 >> 2, lg = g8 & 3;

    const float* ks = k  + (size_t)tt * NF * NG + cout;
    const float* rs = rk + (size_t)tt * NF * NG + cout;

    f16 hi8[8], lo8[8];
#pragma unroll
    for (int j = 0; j < 8; ++j) {
        int cin = kk * 32 + lg * 8 + j;
        float w = ks[(size_t)cin * NG] + rs[(size_t)cin * NG];
        f16 hi = (f16)w;
        hi8[j] = hi;
        lo8[j] = (f16)(w - (float)hi);
    }
    const int lane = lg * 16 + (cout & 15);
    size_t chunk = (size_t)t * WSTEP + (size_t)(tap * 2 + kk) * 2048 +
                   (size_t)(cout >> 4) * 64 + lane;
    *(f16x8*)&wf2[chunk * 8]          = *(f16x8*)hi8;
    *(f16x8*)&wf2[(chunk + 1024) * 8] = *(f16x8*)lo8;
}

// ---- prologue 2: split h0 to fp16 hi/lo, layout [b][y][x][hi(64)|lo(64)]
__global__ void split_h(const float* __restrict__ h0, f16* __restrict__ h2) {
    int idx = blockIdx.x * 256 + threadIdx.x;
    if (idx >= (int)(NB * HWF)) return;
    int f = idx & 63;
    size_t p = (size_t)(idx >> 6);
    float v = h0[idx];
    f16 hi = (f16)v;
    h2[p * 128 + f]      = hi;
    h2[p * 128 + 64 + f] = (f16)(v - (float)hi);
}

// ================= per-step device body (identical math to round 6) =================
__device__ __forceinline__ void step_body(
    const f16* __restrict__ h2in, f16* __restrict__ h2out,
    const float* __restrict__ cprev, float* __restrict__ cnew,
    float* __restrict__ hout, const f16* __restrict__ wt,
    const float* __restrict__ bias,
    unsigned char* lds, int tid, int bb, int y0)
{
    const int w    = tid >> 6;
    const int lane = tid & 63;

    // zero the pad columns sx=0 and sx=65
    if (tid < 128) {
        int row = tid >> 5, side = (tid >> 4) & 1, j = tid & 15;
        *(f16x8*)&lds[row * RS + side * (65 * 256) + j * 16] = (f16x8)(_Float16)0.0f;
    }

    // stage rows y0-1 .. y0+2 with pre-swizzled global source
    {
        const int r    = w >> 1;
        const int gy   = y0 - 1 + r;
        const int half = w & 1;
        const unsigned dbase = r * RS + 256 + half * 8192;
        if (gy >= 0 && gy < NH) {
            const unsigned char* gsrc = (const unsigned char*)h2in +
                ((((size_t)bb * NH + gy) * NW) << 8);
            const int j = lane & 15;
#pragma unroll
            for (int i = 0; i < 8; ++i) {
                const int xrel = half * 32 + i * 4 + (lane >> 4);
                const unsigned src = ((unsigned)xrel << 8) +
                                     ((unsigned)(j ^ ((xrel + 1) & 7)) << 4);
                gload_lds16(gsrc + src, (void*)&lds[dbase + i * 1024]);
            }
        } else {
            const f16x8 zf = (f16x8)(_Float16)0.0f;
#pragma unroll
            for (int i = 0; i < 8; ++i)
                *(f16x8*)&lds[dbase + i * 1024 + lane * 16] = zf;
        }
    }
    __syncthreads();

    // ---------- K loop
    const int wm = w >> 2;
    const int wn = w & 3;
    const int lm = lane & 15;
    const int lg = lane >> 4;

    f32x4 acc[4][4];
#pragma unroll
    for (int mf = 0; mf < 4; ++mf)
#pragma unroll
        for (int nf = 0; nf < 4; ++nf) acc[mf][nf] = (f32x4)0.0f;

    unsigned av[3][2];
#pragma unroll
    for (int d = 0; d < 3; ++d)
#pragma unroll
        for (int kk = 0; kk < 2; ++kk) {
            const int sxl = lm + d;
            av[d][kk] = (unsigned)(sxl * 256 +
                        ((kk * 64 + lg * 16) ^ ((sxl & 7) << 4)));
        }

    const f16x8* wb = (const f16x8*)wt + (size_t)(wn * 4) * 64 + lane;

    f16x8 bh[4], bl[4];

#pragma unroll
    for (int it = 0; it < 18; ++it) {
        const int tap = it >> 1, kk = it & 1;
#pragma unroll
        for (int nf = 0; nf < 4; ++nf) {
            bh[nf] = wb[(size_t)it * 2048 + nf * 64];
            bl[nf] = wb[(size_t)it * 2048 + 1024 + nf * 64];
        }
        const int ty = tap / 3;
        const int d  = tap - ty * 3;
        const unsigned abase = (unsigned)((wm + ty) * RS) + av[d][kk];
        __builtin_amdgcn_s_setprio(1);
#pragma unroll
        for (int mf = 0; mf < 4; ++mf) {
            const f16x8 ah = *(const f16x8*)&lds[abase + mf * 4096];
            const f16x8 al = *(const f16x8*)&lds[abase + mf * 4096 + 128];
#pragma unroll
            for (int nf = 0; nf < 4; ++nf)
                acc[mf][nf] = MFMA(ah, bh[nf], acc[mf][nf]);
#pragma unroll
            for (int nf = 0; nf < 4; ++nf)
                acc[mf][nf] = MFMA(al, bh[nf], acc[mf][nf]);
#pragma unroll
            for (int nf = 0; nf < 4; ++nf)
                acc[mf][nf] = MFMA(ah, bl[nf], acc[mf][nf]);
        }
        __builtin_amdgcn_s_setprio(0);
    }

    __syncthreads();

    // ---------- epilogue
    float* zbuf = (float*)lds;
    const int f = tid & 63;
    const float bi = bias[f], bfv = bias[64 + f], bcv = bias[128 + f], bov = bias[192 + f];

#pragma unroll 1
    for (int half = 0; half < 2; ++half) {
        if (wm == half) {
#pragma unroll
            for (int mf = 0; mf < 4; ++mf)
#pragma unroll
                for (int nf = 0; nf < 4; ++nf)
#pragma unroll
                    for (int j = 0; j < 4; ++j)
                        zbuf[(mf * 16 + lg * 4 + j) * ZS + wn * 64 + nf * 16 + lm] =
                            acc[mf][nf][j];
        }
        __syncthreads();
        const int gy = y0 + half;
#pragma unroll 1
        for (int k2 = 0; k2 < 8; ++k2) {
            const int x = (tid >> 6) + k2 * 8;
            const float* zz = zbuf + x * ZS;
            float zi  = zz[f]       + bi;
            float zfv = zz[64 + f]  + bfv;
            float zc  = zz[128 + f] + bcv;
            float zo  = zz[192 + f] + bov;
            size_t goff = (((size_t)bb * NH + gy) * NW + x) * NF + f;
            float cp = cprev[goff];
            float ig = hsig(zi), fg = hsig(zfv), og = hsig(zo);
            float cn = fg * cp + ig * tanhf(zc);
            cnew[goff] = cn;
            float hn = og * tanhf(cn);
            hout[(size_t)bb * OUT_BSTRIDE + (((size_t)gy * NW + x) * NF + f)] = hn;
            size_t p2 = (((size_t)bb * NH + gy) * NW + x) * 128 + f;
            f16 hi = (f16)hn;
            h2out[p2]      = hi;
            h2out[p2 + 64] = (f16)(hn - (float)hi);
        }
        __syncthreads();
    }
}

// ================= persistent kernel: neighbor-flag pipelined steps =================
__global__ void __launch_bounds__(512, 4)
convlstm_persist(const f16* __restrict__ wf2,
                 f16* __restrict__ h2a, f16* __restrict__ h2b,
                 const float* __restrict__ c0, float* __restrict__ cbuf,
                 float* __restrict__ out, const float* __restrict__ bias_all,
                 int* __restrict__ flags)
{
    __shared__ __align__(16) unsigned char lds[4 * RS];

    const int tid = threadIdx.x;
    const int iy  = blockIdx.x;         // 0..31
    const int bb  = blockIdx.y;         // 0..15
    const int y0  = iy * 2;

#pragma unroll 1
    for (int t = 0; t < NT; ++t) {
        // wait for y-neighbors to finish step t-1 (their h2 rows are our halo)
        if (t > 0) {
            if (tid == 0) {
                const int base = ((t - 1) * 512 + bb * 32) * FSTRIDE;
                if (iy > 0)
                    while (__hip_atomic_load(&flags[base + (iy - 1) * FSTRIDE],
                           __ATOMIC_ACQUIRE, __HIP_MEMORY_SCOPE_AGENT) == 0)
                        __builtin_amdgcn_s_sleep(1);
                if (iy < 31)
                    while (__hip_atomic_load(&flags[base + (iy + 1) * FSTRIDE],
                           __ATOMIC_ACQUIRE, __HIP_MEMORY_SCOPE_AGENT) == 0)
                        __builtin_amdgcn_s_sleep(1);
            }
            __syncthreads();
            __threadfence();   // invalidate stale caches before reading neighbor h2
        }

        const f16* h2in  = (t & 1) ? h2b : h2a;
        f16*       h2out = (t & 1) ? h2a : h2b;
        step_body(h2in, h2out,
                  (t == 0) ? c0 : cbuf, cbuf,
                  out + (size_t)t * HWF,
                  wf2 + (size_t)t * WSTEP * 8,
                  bias_all + t * NG,
                  lds, tid, bb, y0);

        // publish: my h2 rows for step t are globally visible
        __threadfence();
        __syncthreads();
        if (tid == 0)
            __hip_atomic_store(&flags[(t * 512 + bb * 32 + iy) * FSTRIDE], 1,
                               __ATOMIC_RELEASE, __HIP_MEMORY_SCOPE_AGENT);
    }
}

// ================= fallback: one step per launch (round-6 proven path) =============
__global__ void __launch_bounds__(512, 4)
convlstm_mfma_step(const f16* __restrict__ h2in, f16* __restrict__ h2out,
                   const float* __restrict__ cprev, float* __restrict__ cnew,
                   float* __restrict__ hout, const f16* __restrict__ wt,
                   const float* __restrict__ bias)
{
    __shared__ __align__(16) unsigned char lds[4 * RS];
    step_body(h2in, h2out, cprev, cnew, hout, wt, bias,
              lds, threadIdx.x, blockIdx.y, blockIdx.x * 2);
}

extern "C" void kernel_launch(void* const* d_in, const int* in_sizes, int n_in,
                              void* d_out, int out_size, void* d_ws, size_t ws_size,
                              hipStream_t stream) {
    const float* h0    = (const float*)d_in[1];
    const float* c0    = (const float*)d_in[2];
    const float* kern  = (const float*)d_in[3];
    const float* rkern = (const float*)d_in[4];
    const float* bias  = (const float*)d_in[5];
    float* out = (float*)d_out;

    f16* wf2 = (f16*)d_ws;                                    // 9.4 MB
    f16* h2a = wf2 + (size_t)NT * WSTEP * 8;                  // 16.8 MB
    f16* h2b = h2a + (size_t)NB * NH * NW * 128;              // 16.8 MB
    float* cbuf = (float*)(h2b + (size_t)NB * NH * NW * 128); // 16.8 MB
    int* flags  = (int*)(cbuf + NB * HWF);                    // 512 KB

    zero_flags<<<NT * 512 * FSTRIDE / 256, 256, 0, stream>>>(flags);
    fuse_split_w<<<(NT * 9 * NG * 8 + 255) / 256, 256, 0, stream>>>(kern, rkern, wf2);
    split_h<<<((int)(NB * HWF) + 255) / 256, 256, 0, stream>>>(h0, h2a);

    const f16* wf2c = wf2;
    const float* c0c = c0;
    const float* biasc = bias;
    void* args[] = { (void*)&wf2c, (void*)&h2a, (void*)&h2b,
                     (void*)&c0c, (void*)&cbuf, (void*)&out, (void*)&biasc,
                     (void*)&flags };
    hipError_t ce = hipLaunchCooperativeKernel(
        (const void*)convlstm_persist, dim3(NH / 2, NB), dim3(512),
        args, 0u, stream);

    if (ce != hipSuccess) {
        (void)hipGetLastError();
        dim3 grid(NH / 2, NB);
        for (int t = 0; t < NT; ++t) {
            const f16* hin = (t & 1) ? h2b : h2a;
            f16* hnx       = (t & 1) ? h2a : h2b;
            convlstm_mfma_step<<<grid, 512, 0, stream>>>(
                hin, hnx,
                (t == 0) ? c0 : cbuf, cbuf,
                out + (size_t)t * HWF,
                wf2 + (size_t)t * WSTEP * 8,
                bias + t * NG);
        }
    }
}

// Round 8
// 1107.736 us; speedup vs baseline: 4.7205x; 4.7205x over previous
//
#include <hip/hip_runtime.h>
#include <math.h>

typedef _Float16 f16;
typedef _Float16 f16x8 __attribute__((ext_vector_type(8)));
typedef float f32x4 __attribute__((ext_vector_type(4)));

#define NB 16      // batch
#define NT 16      // time steps
#define NH 64
#define NW 64
#define NF 64      // features
#define NG 256     // 4*F
#define HWF ((size_t)NH * NW * NF)          // 262144
#define OUT_BSTRIDE ((size_t)NT * HWF)      // d_out batch stride
#define RS 16896                            // LDS row stride = 66 * 256 B (x-padded)
#define ZS 258                              // zbuf row stride in floats
#define WSTEP ((size_t)36864)               // per-step wf2 size in f16x8 chunks

#define MFMA(a, b, c) __builtin_amdgcn_mfma_f32_16x16x32_f16((a), (b), (c), 0, 0, 0)

__device__ __forceinline__ void gload_lds16(const void* g, void* l) {
    __builtin_amdgcn_global_load_lds(
        (const __attribute__((address_space(1))) unsigned int*)(g),
        (__attribute__((address_space(3))) unsigned int*)(l), 16, 0, 0);
}

__device__ __forceinline__ float hsig(float x) {
    return fminf(fmaxf(0.2f * x + 0.5f, 0.0f), 1.0f);
}

// fast tanh via v_exp_f32: tanh(x) = 1 - 2/(2^(2x*log2e)+1). ~2e-7 abs err.
__device__ __forceinline__ float ftanh(float x) {
    float t = __builtin_amdgcn_exp2f(x * 2.885390081777927f);
    return 1.0f - 2.0f * __builtin_amdgcn_rcpf(t + 1.0f);
}

// ---- prologue 1: fuse W+U, split fp16 hi/lo, lane-ordered chunks:
// chunk (f16x8 units): (tap*2+kk)*2048 + term*1024 + (cout>>4)*64 + lane
// lane = lg*16 + (cout&15) holds cin = kk*32 + lg*8 .. +7.
__global__ void fuse_split_w(const float* __restrict__ k, const float* __restrict__ rk,
                             f16* __restrict__ wf2) {
    int idx = blockIdx.x * 256 + threadIdx.x;      // over 16*9*256*8 = 294912
    if (idx >= NT * 9 * NG * 8) return;
    int g8   = idx & 7;
    int cout = (idx >> 3) & 255;
    int tt   = idx >> 11;          // t*9 + tap
    int tap  = tt % 9;
    int t    = tt / 9;
    int kk = g8 >> 2, lg = g8 & 3;

    const float* ks = k  + (size_t)tt * NF * NG + cout;
    const float* rs = rk + (size_t)tt * NF * NG + cout;

    f16 hi8[8], lo8[8];
#pragma unroll
    for (int j = 0; j < 8; ++j) {
        int cin = kk * 32 + lg * 8 + j;
        float w = ks[(size_t)cin * NG] + rs[(size_t)cin * NG];
        f16 hi = (f16)w;
        hi8[j] = hi;
        lo8[j] = (f16)(w - (float)hi);
    }
    const int lane = lg * 16 + (cout & 15);
    size_t chunk = (size_t)t * WSTEP + (size_t)(tap * 2 + kk) * 2048 +
                   (size_t)(cout >> 4) * 64 + lane;
    *(f16x8*)&wf2[chunk * 8]          = *(f16x8*)hi8;
    *(f16x8*)&wf2[(chunk + 1024) * 8] = *(f16x8*)lo8;
}

// ---- prologue 2: split h0 to fp16 hi/lo, layout [b][y][x][hi(64)|lo(64)]
__global__ void split_h(const float* __restrict__ h0, f16* __restrict__ h2) {
    int idx = blockIdx.x * 256 + threadIdx.x;
    if (idx >= (int)(NB * HWF)) return;
    int f = idx & 63;
    size_t p = (size_t)(idx >> 6);
    float v = h0[idx];
    f16 hi = (f16)v;
    h2[p * 128 + f]      = hi;
    h2[p * 128 + 64 + f] = (f16)(v - (float)hi);
}

// ---- one ConvLSTM step. 512 threads = 8 waves, each wave = one 32-wide n-slice
// over all M=128 positions (2 rows x 64 x). B weights are read EXACTLY ONCE per
// block (no m-wave duplication) — halves per-XCD L2 weight traffic.
__global__ void __launch_bounds__(512, 4)
convlstm_mfma_step(const f16* __restrict__ h2in, f16* __restrict__ h2out,
                   const float* __restrict__ cprev, float* __restrict__ cnew,
                   float* __restrict__ hout,        // d_out + t*HWF
                   const f16* __restrict__ wt,      // lane-ordered chunks for this t
                   const float* __restrict__ bias)  // [256] for this t
{
    __shared__ __align__(16) unsigned char lds[4 * RS];   // 67584 B

    const int tid  = threadIdx.x;
    const int w    = tid >> 6;
    const int lane = tid & 63;
    const int bb   = blockIdx.y;
    const int y0   = blockIdx.x * 2;

    // zero the pad columns sx=0 and sx=65
    if (tid < 128) {
        int row = tid >> 5, side = (tid >> 4) & 1, j = tid & 15;
        *(f16x8*)&lds[row * RS + side * (65 * 256) + j * 16] = (f16x8)(_Float16)0.0f;
    }

    // stage rows y0-1 .. y0+2 with pre-swizzled global source (rule 21)
    {
        const int r    = w >> 1;
        const int gy   = y0 - 1 + r;
        const int half = w & 1;
        const unsigned dbase = r * RS + 256 + half * 8192;
        if (gy >= 0 && gy < NH) {
            const unsigned char* gsrc = (const unsigned char*)h2in +
                ((((size_t)bb * NH + gy) * NW) << 8);
            const int j = lane & 15;
#pragma unroll
            for (int i = 0; i < 8; ++i) {
                const int xrel = half * 32 + i * 4 + (lane >> 4);
                const unsigned src = ((unsigned)xrel << 8) +
                                     ((unsigned)(j ^ ((xrel + 1) & 7)) << 4);
                gload_lds16(gsrc + src, (void*)&lds[dbase + i * 1024]);
            }
        } else {
            const f16x8 zf = (f16x8)(_Float16)0.0f;
#pragma unroll
            for (int i = 0; i < 8; ++i)
                *(f16x8*)&lds[dbase + i * 1024 + lane * 16] = zf;
        }
    }
    __syncthreads();

    // ---------- K loop: 9 taps x 2 cin-halves, fully unrolled, 3-term split MFMA
    const int lm = lane & 15;
    const int lg = lane >> 4;

    f32x4 acc[8][2];           // mf = row*4 + xblk (M=128), nf = n-frag (N=32)
#pragma unroll
    for (int mf = 0; mf < 8; ++mf)
#pragma unroll
        for (int nf = 0; nf < 2; ++nf) acc[mf][nf] = (f32x4)0.0f;

    unsigned av[3][2];
#pragma unroll
    for (int d = 0; d < 3; ++d)
#pragma unroll
        for (int kk = 0; kk < 2; ++kk) {
            const int sxl = lm + d;
            av[d][kk] = (unsigned)(sxl * 256 +
                        ((kk * 64 + lg * 16) ^ ((sxl & 7) << 4)));
        }

    // this wave's B slice: cout blocks w*2 and w*2+1
    const f16x8* wb = (const f16x8*)wt + (size_t)(w * 2) * 64 + lane;

    f16x8 bh[2], bl[2];

#pragma unroll
    for (int it = 0; it < 18; ++it) {
        const int tap = it >> 1, kk = it & 1;
#pragma unroll
        for (int nf = 0; nf < 2; ++nf) {
            bh[nf] = wb[(size_t)it * 2048 + nf * 64];
            bl[nf] = wb[(size_t)it * 2048 + 1024 + nf * 64];
        }
        const int ty = tap / 3;
        const int d  = tap - ty * 3;
        const unsigned abase = av[d][kk];
        // mf pairs: 4 A ds_reads then 12 MFMAs (dep distance 4)
#pragma unroll
        for (int mfp = 0; mfp < 4; ++mfp) {
            const int mf0 = 2 * mfp, mf1 = 2 * mfp + 1;
            const unsigned a0 = (unsigned)(((mf0 >> 2) + ty) * RS + (mf0 & 3) * 4096) + abase;
            const unsigned a1 = (unsigned)(((mf1 >> 2) + ty) * RS + (mf1 & 3) * 4096) + abase;
            const f16x8 ah0 = *(const f16x8*)&lds[a0];
            const f16x8 al0 = *(const f16x8*)&lds[a0 + 128];
            const f16x8 ah1 = *(const f16x8*)&lds[a1];
            const f16x8 al1 = *(const f16x8*)&lds[a1 + 128];
            __builtin_amdgcn_s_setprio(1);
            acc[mf0][0] = MFMA(ah0, bh[0], acc[mf0][0]);
            acc[mf0][1] = MFMA(ah0, bh[1], acc[mf0][1]);
            acc[mf1][0] = MFMA(ah1, bh[0], acc[mf1][0]);
            acc[mf1][1] = MFMA(ah1, bh[1], acc[mf1][1]);
            acc[mf0][0] = MFMA(al0, bh[0], acc[mf0][0]);
            acc[mf0][1] = MFMA(al0, bh[1], acc[mf0][1]);
            acc[mf1][0] = MFMA(al1, bh[0], acc[mf1][0]);
            acc[mf1][1] = MFMA(al1, bh[1], acc[mf1][1]);
            acc[mf0][0] = MFMA(ah0, bl[0], acc[mf0][0]);
            acc[mf0][1] = MFMA(ah0, bl[1], acc[mf0][1]);
            acc[mf1][0] = MFMA(ah1, bl[0], acc[mf1][0]);
            acc[mf1][1] = MFMA(ah1, bl[1], acc[mf1][1]);
            __builtin_amdgcn_s_setprio(0);
        }
    }

    __syncthreads();

    // ---------- epilogue: z-exchange through LDS (all 8 waves write each half),
    // fused LSTM pointwise with fast tanh.
    float* zbuf = (float*)lds;
    const int f = tid & 63;
    const float bi = bias[f], bfv = bias[64 + f], bcv = bias[128 + f], bov = bias[192 + f];

#pragma unroll 1
    for (int half = 0; half < 2; ++half) {
#pragma unroll
        for (int xb = 0; xb < 4; ++xb) {
            const int mf = half * 4 + xb;
#pragma unroll
            for (int nf = 0; nf < 2; ++nf)
#pragma unroll
                for (int j = 0; j < 4; ++j)
                    zbuf[(xb * 16 + lg * 4 + j) * ZS + w * 32 + nf * 16 + lm] =
                        acc[mf][nf][j];
        }
        __syncthreads();
        const int gy = y0 + half;
#pragma unroll 1
        for (int k2 = 0; k2 < 8; ++k2) {
            const int x = (tid >> 6) + k2 * 8;
            const float* zz = zbuf + x * ZS;
            float zi  = zz[f]       + bi;
            float zfv = zz[64 + f]  + bfv;
            float zc  = zz[128 + f] + bcv;
            float zo  = zz[192 + f] + bov;
            size_t goff = (((size_t)bb * NH + gy) * NW + x) * NF + f;
            float cp = cprev[goff];
            float ig = hsig(zi), fg = hsig(zfv), og = hsig(zo);
            float cn = fg * cp + ig * ftanh(zc);
            cnew[goff] = cn;
            float hn = og * ftanh(cn);
            hout[(size_t)bb * OUT_BSTRIDE + (((size_t)gy * NW + x) * NF + f)] = hn;
            size_t p2 = (((size_t)bb * NH + gy) * NW + x) * 128 + f;
            f16 hi = (f16)hn;
            h2out[p2]      = hi;
            h2out[p2 + 64] = (f16)(hn - (float)hi);
        }
        __syncthreads();
    }
}

extern "C" void kernel_launch(void* const* d_in, const int* in_sizes, int n_in,
                              void* d_out, int out_size, void* d_ws, size_t ws_size,
                              hipStream_t stream) {
    const float* h0    = (const float*)d_in[1];
    const float* c0    = (const float*)d_in[2];
    const float* kern  = (const float*)d_in[3];
    const float* rkern = (const float*)d_in[4];
    const float* bias  = (const float*)d_in[5];
    float* out = (float*)d_out;

    f16* wf2 = (f16*)d_ws;                                    // 9.4 MB
    f16* h2a = wf2 + (size_t)NT * WSTEP * 8;                  // 16.8 MB
    f16* h2b = h2a + (size_t)NB * NH * NW * 128;              // 16.8 MB
    float* cbuf = (float*)(h2b + (size_t)NB * NH * NW * 128); // 16.8 MB

    fuse_split_w<<<(NT * 9 * NG * 8 + 255) / 256, 256, 0, stream>>>(kern, rkern, wf2);
    split_h<<<((int)(NB * HWF) + 255) / 256, 256, 0, stream>>>(h0, h2a);

    dim3 grid(NH / 2, NB);
    for (int t = 0; t < NT; ++t) {
        const f16* hin = (t & 1) ? h2b : h2a;
        f16* hnx       = (t & 1) ? h2a : h2b;
        convlstm_mfma_step<<<grid, 512, 0, stream>>>(
            hin, hnx,
            (t == 0) ? c0 : cbuf, cbuf,
            out + (size_t)t * HWF,
            wf2 + (size_t)t * WSTEP * 8,
            bias + t * NG);
    }
}

// Round 9
// 676.816 us; speedup vs baseline: 7.7260x; 1.6367x over previous
//
#include <hip/hip_runtime.h>
#include <math.h>

typedef _Float16 f16;
typedef _Float16 f16x8 __attribute__((ext_vector_type(8)));
typedef float f32x4 __attribute__((ext_vector_type(4)));

#define NB 16      // batch
#define NT 16      // time steps
#define NH 64
#define NW 64
#define NF 64      // features
#define NG 256     // 4*F
#define HWF ((size_t)NH * NW * NF)          // 262144
#define OUT_BSTRIDE ((size_t)NT * HWF)      // d_out batch stride
#define RS 16896                            // LDS row stride = 66 * 256 B (x-padded)
#define ZS 258                              // zbuf row stride in floats
#define WSTEP ((size_t)36864)               // per-step wf2 size in f16x8 chunks

#define MFMA(a, b, c) __builtin_amdgcn_mfma_f32_16x16x32_f16((a), (b), (c), 0, 0, 0)

__device__ __forceinline__ void gload_lds16(const void* g, void* l) {
    __builtin_amdgcn_global_load_lds(
        (const __attribute__((address_space(1))) unsigned int*)(g),
        (__attribute__((address_space(3))) unsigned int*)(l), 16, 0, 0);
}

__device__ __forceinline__ float hsig(float x) {
    return fminf(fmaxf(0.2f * x + 0.5f, 0.0f), 1.0f);
}

// fast tanh via v_exp_f32: tanh(x) = 1 - 2/(2^(2x*log2e)+1). ~2e-7 abs err.
// (round 8 verified absmax-neutral)
__device__ __forceinline__ float ftanh(float x) {
    float t = __builtin_amdgcn_exp2f(x * 2.885390081777927f);
    return 1.0f - 2.0f * __builtin_amdgcn_rcpf(t + 1.0f);
}

// ---- prologue 1: fuse W+U, split fp16 hi/lo, lane-ordered chunks:
// chunk (f16x8 units): (tap*2+kk)*2048 + term*1024 + (cout>>4)*64 + lane
// lane = lg*16 + (cout&15) holds cin = kk*32 + lg*8 .. +7.
__global__ void fuse_split_w(const float* __restrict__ k, const float* __restrict__ rk,
                             f16* __restrict__ wf2) {
    int idx = blockIdx.x * 256 + threadIdx.x;      // over 16*9*256*8 = 294912
    if (idx >= NT * 9 * NG * 8) return;
    int g8   = idx & 7;
    int cout = (idx >> 3) & 255;
    int tt   = idx >> 11;          // t*9 + tap
    int tap  = tt % 9;
    int t    = tt / 9;
    int kk = g8 >> 2, lg = g8 & 3;

    const float* ks = k  + (size_t)tt * NF * NG + cout;
    const float* rs = rk + (size_t)tt * NF * NG + cout;

    f16 hi8[8], lo8[8];
#pragma unroll
    for (int j = 0; j < 8; ++j) {
        int cin = kk * 32 + lg * 8 + j;
        float w = ks[(size_t)cin * NG] + rs[(size_t)cin * NG];
        f16 hi = (f16)w;
        hi8[j] = hi;
        lo8[j] = (f16)(w - (float)hi);
    }
    const int lane = lg * 16 + (cout & 15);
    size_t chunk = (size_t)t * WSTEP + (size_t)(tap * 2 + kk) * 2048 +
                   (size_t)(cout >> 4) * 64 + lane;
    *(f16x8*)&wf2[chunk * 8]          = *(f16x8*)hi8;
    *(f16x8*)&wf2[(chunk + 1024) * 8] = *(f16x8*)lo8;
}

// ---- prologue 2: split h0 to fp16 hi/lo, layout [b][y][x][hi(64)|lo(64)]
__global__ void split_h(const float* __restrict__ h0, f16* __restrict__ h2) {
    int idx = blockIdx.x * 256 + threadIdx.x;
    if (idx >= (int)(NB * HWF)) return;
    int f = idx & 63;
    size_t p = (size_t)(idx >> 6);
    float v = h0[idx];
    f16 hi = (f16)v;
    h2[p * 128 + f]      = hi;
    h2[p * 128 + 64 + f] = (f16)(v - (float)hi);
}

// ---- one ConvLSTM step. Round-6 wave mapping (2m x 4n), gate-dependent precision:
// wn==2 (c-gate) waves: 3-term split-fp16 (full precision into cell state);
// wn!=2 (i,f,o) waves: 1-term hi*hi (hard_sigmoid tolerates ~1.6e-3 z error).
// Halves block MFMA count (384->192/iter), A-LDS reads (64->40), B-L2 (0.63x).
__global__ void __launch_bounds__(512, 4)
convlstm_mfma_step(const f16* __restrict__ h2in, f16* __restrict__ h2out,
                   const float* __restrict__ cprev, float* __restrict__ cnew,
                   float* __restrict__ hout,        // d_out + t*HWF
                   const f16* __restrict__ wt,      // lane-ordered chunks for this t
                   const float* __restrict__ bias)  // [256] for this t
{
    __shared__ __align__(16) unsigned char lds[4 * RS];   // 67584 B

    const int tid  = threadIdx.x;
    const int w    = tid >> 6;
    const int lane = tid & 63;
    const int bb   = blockIdx.y;
    const int y0   = blockIdx.x * 2;

    // zero the pad columns sx=0 and sx=65
    if (tid < 128) {
        int row = tid >> 5, side = (tid >> 4) & 1, j = tid & 15;
        *(f16x8*)&lds[row * RS + side * (65 * 256) + j * 16] = (f16x8)(_Float16)0.0f;
    }

    // stage rows y0-1 .. y0+2 with pre-swizzled global source (rule 21)
    {
        const int r    = w >> 1;
        const int gy   = y0 - 1 + r;
        const int half = w & 1;
        const unsigned dbase = r * RS + 256 + half * 8192;
        if (gy >= 0 && gy < NH) {
            const unsigned char* gsrc = (const unsigned char*)h2in +
                ((((size_t)bb * NH + gy) * NW) << 8);
            const int j = lane & 15;
#pragma unroll
            for (int i = 0; i < 8; ++i) {
                const int xrel = half * 32 + i * 4 + (lane >> 4);
                const unsigned src = ((unsigned)xrel << 8) +
                                     ((unsigned)(j ^ ((xrel + 1) & 7)) << 4);
                gload_lds16(gsrc + src, (void*)&lds[dbase + i * 1024]);
            }
        } else {
            const f16x8 zf = (f16x8)(_Float16)0.0f;
#pragma unroll
            for (int i = 0; i < 8; ++i)
                *(f16x8*)&lds[dbase + i * 1024 + lane * 16] = zf;
        }
    }
    __syncthreads();

    // ---------- K loop: 9 taps x 2 cin-halves, fully unrolled
    const int wm = w >> 2;
    const int wn = w & 3;
    const int lm = lane & 15;
    const int lg = lane >> 4;

    f32x4 acc[4][4];
#pragma unroll
    for (int mf = 0; mf < 4; ++mf)
#pragma unroll
        for (int nf = 0; nf < 4; ++nf) acc[mf][nf] = (f32x4)0.0f;

    unsigned av[3][2];
#pragma unroll
    for (int d = 0; d < 3; ++d)
#pragma unroll
        for (int kk = 0; kk < 2; ++kk) {
            const int sxl = lm + d;
            av[d][kk] = (unsigned)(sxl * 256 +
                        ((kk * 64 + lg * 16) ^ ((sxl & 7) << 4)));
        }

    const f16x8* wb = (const f16x8*)wt + (size_t)(wn * 4) * 64 + lane;

    if (wn == 2) {
        // ---- c-gate: 3-term split (hi*hi + lo*hi + hi*lo)
        f16x8 bh[4], bl[4];
#pragma unroll
        for (int it = 0; it < 18; ++it) {
            const int tap = it >> 1, kk = it & 1;
#pragma unroll
            for (int nf = 0; nf < 4; ++nf) {
                bh[nf] = wb[(size_t)it * 2048 + nf * 64];
                bl[nf] = wb[(size_t)it * 2048 + 1024 + nf * 64];
            }
            const int ty = tap / 3;
            const int d  = tap - ty * 3;
            const unsigned abase = (unsigned)((wm + ty) * RS) + av[d][kk];
            __builtin_amdgcn_s_setprio(1);
#pragma unroll
            for (int mf = 0; mf < 4; ++mf) {
                const f16x8 ah = *(const f16x8*)&lds[abase + mf * 4096];
                const f16x8 al = *(const f16x8*)&lds[abase + mf * 4096 + 128];
#pragma unroll
                for (int nf = 0; nf < 4; ++nf)
                    acc[mf][nf] = MFMA(ah, bh[nf], acc[mf][nf]);
#pragma unroll
                for (int nf = 0; nf < 4; ++nf)
                    acc[mf][nf] = MFMA(al, bh[nf], acc[mf][nf]);
#pragma unroll
                for (int nf = 0; nf < 4; ++nf)
                    acc[mf][nf] = MFMA(ah, bl[nf], acc[mf][nf]);
            }
            __builtin_amdgcn_s_setprio(0);
        }
    } else {
        // ---- i/f/o gates: 1-term (hi*hi)
        f16x8 bh[4];
#pragma unroll
        for (int it = 0; it < 18; ++it) {
            const int tap = it >> 1, kk = it & 1;
#pragma unroll
            for (int nf = 0; nf < 4; ++nf)
                bh[nf] = wb[(size_t)it * 2048 + nf * 64];
            const int ty = tap / 3;
            const int d  = tap - ty * 3;
            const unsigned abase = (unsigned)((wm + ty) * RS) + av[d][kk];
            __builtin_amdgcn_s_setprio(1);
#pragma unroll
            for (int mf = 0; mf < 4; ++mf) {
                const f16x8 ah = *(const f16x8*)&lds[abase + mf * 4096];
#pragma unroll
                for (int nf = 0; nf < 4; ++nf)
                    acc[mf][nf] = MFMA(ah, bh[nf], acc[mf][nf]);
            }
            __builtin_amdgcn_s_setprio(0);
        }
    }

    __syncthreads();

    // ---------- epilogue: z-exchange through LDS, fused LSTM pointwise
    float* zbuf = (float*)lds;
    const int f = tid & 63;
    const float bi = bias[f], bfv = bias[64 + f], bcv = bias[128 + f], bov = bias[192 + f];

#pragma unroll 1
    for (int half = 0; half < 2; ++half) {
        if (wm == half) {
#pragma unroll
            for (int mf = 0; mf < 4; ++mf)
#pragma unroll
                for (int nf = 0; nf < 4; ++nf)
#pragma unroll
                    for (int j = 0; j < 4; ++j)
                        zbuf[(mf * 16 + lg * 4 + j) * ZS + wn * 64 + nf * 16 + lm] =
                            acc[mf][nf][j];
        }
        __syncthreads();
        const int gy = y0 + half;
#pragma unroll 1
        for (int k2 = 0; k2 < 8; ++k2) {
            const int x = (tid >> 6) + k2 * 8;
            const float* zz = zbuf + x * ZS;
            float zi  = zz[f]       + bi;
            float zfv = zz[64 + f]  + bfv;
            float zc  = zz[128 + f] + bcv;
            float zo  = zz[192 + f] + bov;
            size_t goff = (((size_t)bb * NH + gy) * NW + x) * NF + f;
            float cp = cprev[goff];
            float ig = hsig(zi), fg = hsig(zfv), og = hsig(zo);
            float cn = fg * cp + ig * ftanh(zc);
            cnew[goff] = cn;
            float hn = og * ftanh(cn);
            hout[(size_t)bb * OUT_BSTRIDE + (((size_t)gy * NW + x) * NF + f)] = hn;
            size_t p2 = (((size_t)bb * NH + gy) * NW + x) * 128 + f;
            f16 hi = (f16)hn;
            h2out[p2]      = hi;
            h2out[p2 + 64] = (f16)(hn - (float)hi);
        }
        __syncthreads();
    }
}

extern "C" void kernel_launch(void* const* d_in, const int* in_sizes, int n_in,
                              void* d_out, int out_size, void* d_ws, size_t ws_size,
                              hipStream_t stream) {
    const float* h0    = (const float*)d_in[1];
    const float* c0    = (const float*)d_in[2];
    const float* kern  = (const float*)d_in[3];
    const float* rkern = (const float*)d_in[4];
    const float* bias  = (const float*)d_in[5];
    float* out = (float*)d_out;

    f16* wf2 = (f16*)d_ws;                                    // 9.4 MB
    f16* h2a = wf2 + (size_t)NT * WSTEP * 8;                  // 16.8 MB
    f16* h2b = h2a + (size_t)NB * NH * NW * 128;              // 16.8 MB
    float* cbuf = (float*)(h2b + (size_t)NB * NH * NW * 128); // 16.8 MB

    fuse_split_w<<<(NT * 9 * NG * 8 + 255) / 256, 256, 0, stream>>>(kern, rkern, wf2);
    split_h<<<((int)(NB * HWF) + 255) / 256, 256, 0, stream>>>(h0, h2a);

    dim3 grid(NH / 2, NB);
    for (int t = 0; t < NT; ++t) {
        const f16* hin = (t & 1) ? h2b : h2a;
        f16* hnx       = (t & 1) ? h2a : h2b;
        convlstm_mfma_step<<<grid, 512, 0, stream>>>(
            hin, hnx,
            (t == 0) ? c0 : cbuf, cbuf,
            out + (size_t)t * HWF,
            wf2 + (size_t)t * WSTEP * 8,
            bias + t * NG);
    }
}

// Round 10
// 558.710 us; speedup vs baseline: 9.3592x; 1.2114x over previous
//
#include <hip/hip_runtime.h>
#include <math.h>

typedef _Float16 f16;
typedef _Float16 f16x8 __attribute__((ext_vector_type(8)));
typedef float f32x4 __attribute__((ext_vector_type(4)));

#define NB 16      // batch
#define NT 16      // time steps
#define NH 64
#define NW 64
#define NF 64      // features
#define NG 256     // 4*F
#define HWF ((size_t)NH * NW * NF)          // 262144
#define OUT_BSTRIDE ((size_t)NT * HWF)      // d_out batch stride
#define RS2 8448                            // LDS row stride = 66 * 128 B (x-padded, f16 h)
#define ZS 258                              // zbuf row stride in floats
#define WSTEP ((size_t)36864)               // per-step wf2 size in f16x8 chunks

#define MFMA(a, b, c) __builtin_amdgcn_mfma_f32_16x16x32_f16((a), (b), (c), 0, 0, 0)

__device__ __forceinline__ void gload_lds16(const void* g, void* l) {
    __builtin_amdgcn_global_load_lds(
        (const __attribute__((address_space(1))) unsigned int*)(g),
        (__attribute__((address_space(3))) unsigned int*)(l), 16, 0, 0);
}

__device__ __forceinline__ float hsig(float x) {
    return fminf(fmaxf(0.2f * x + 0.5f, 0.0f), 1.0f);
}

// fast tanh via v_exp_f32 (round 8/9 verified absmax-neutral)
__device__ __forceinline__ float ftanh(float x) {
    float t = __builtin_amdgcn_exp2f(x * 2.885390081777927f);
    return 1.0f - 2.0f * __builtin_amdgcn_rcpf(t + 1.0f);
}

// ---- prologue 1: fuse W+U, split fp16 hi/lo, lane-ordered chunks:
// chunk (f16x8 units): (tap*2+kk)*2048 + term*1024 + (cout>>4)*64 + lane
// lane = lg*16 + (cout&15) holds cin = kk*32 + lg*8 .. +7.
// (lo terms only consumed for the c-gate now, but built for all — harmless)
__global__ void fuse_split_w(const float* __restrict__ k, const float* __restrict__ rk,
                             f16* __restrict__ wf2) {
    int idx = blockIdx.x * 256 + threadIdx.x;      // over 16*9*256*8 = 294912
    if (idx >= NT * 9 * NG * 8) return;
    int g8   = idx & 7;
    int cout = (idx >> 3) & 255;
    int tt   = idx >> 11;          // t*9 + tap
    int tap  = tt % 9;
    int t    = tt / 9;
    int kk = g8 >> 2, lg = g8 & 3;

    const float* ks = k  + (size_t)tt * NF * NG + cout;
    const float* rs = rk + (size_t)tt * NF * NG + cout;

    f16 hi8[8], lo8[8];
#pragma unroll
    for (int j = 0; j < 8; ++j) {
        int cin = kk * 32 + lg * 8 + j;
        float w = ks[(size_t)cin * NG] + rs[(size_t)cin * NG];
        f16 hi = (f16)w;
        hi8[j] = hi;
        lo8[j] = (f16)(w - (float)hi);
    }
    const int lane = lg * 16 + (cout & 15);
    size_t chunk = (size_t)t * WSTEP + (size_t)(tap * 2 + kk) * 2048 +
                   (size_t)(cout >> 4) * 64 + lane;
    *(f16x8*)&wf2[chunk * 8]          = *(f16x8*)hi8;
    *(f16x8*)&wf2[(chunk + 1024) * 8] = *(f16x8*)lo8;
}

// ---- prologue 2: h0 -> plain f16, layout [b][y][x][64]
__global__ void split_h(const float* __restrict__ h0, f16* __restrict__ h2) {
    int idx = blockIdx.x * 256 + threadIdx.x;
    if (idx >= (int)(NB * HWF)) return;
    h2[idx] = (f16)h0[idx];
}

// ---- one ConvLSTM step. 8 waves (2m x 4n); gate-dependent precision:
// c-gate wave: 2-term h_f16*(w_hi + w_lo) (576 MFMA); i/f/o: 1-term (288 MFMA).
// wn permuted for wm=1 (+2) so the two heavy c-waves land on different SIMDs.
// h tile is f16-only: [4 rows][tx 0..65][8 granules of 16B], slot = g ^ (tx&7).
__global__ void __launch_bounds__(512, 4)
convlstm_mfma_step(const f16* __restrict__ h2in, f16* __restrict__ h2out,
                   const float* __restrict__ cprev, float* __restrict__ cnew,
                   float* __restrict__ hout,        // d_out + t*HWF
                   const f16* __restrict__ wt,      // lane-ordered chunks for this t
                   const float* __restrict__ bias)  // [256] for this t
{
    __shared__ __align__(16) unsigned char lds[67584];

    const int tid  = threadIdx.x;
    const int w    = tid >> 6;
    const int lane = tid & 63;
    const int bb   = blockIdx.y;
    const int y0   = blockIdx.x * 2;

    // zero the pad columns tx=0 and tx=65 (4 rows x 2 x 128B)
    if (tid < 64) {
        int row = tid >> 4, side = (tid >> 3) & 1, j = tid & 7;
        *(f16x8*)&lds[row * RS2 + side * (65 * 128) + j * 16] = (f16x8)(_Float16)0.0f;
    }

    // stage rows y0-1 .. y0+2 (f16, 128B per (y,x)); pre-swizzled global source
    {
        const int r    = w >> 1;               // tile row 0..3
        const int gy   = y0 - 1 + r;
        const int half = w & 1;
        const unsigned dbase = r * RS2 + 128 + half * 4096;  // wave-uniform
        if (gy >= 0 && gy < NH) {
            const unsigned char* gsrc = (const unsigned char*)h2in +
                ((((size_t)bb * NH + gy) * NW) << 7);        // 128 B per (y,x)
#pragma unroll
            for (int i = 0; i < 4; ++i) {
                const int xrel = half * 32 + i * 8 + (lane >> 3);
                const unsigned src = ((unsigned)xrel << 7) +
                    ((unsigned)((lane & 7) ^ ((xrel + 1) & 7)) << 4);
                gload_lds16(gsrc + src, (void*)&lds[dbase + i * 1024]);
            }
        } else {
            const f16x8 zf = (f16x8)(_Float16)0.0f;
#pragma unroll
            for (int i = 0; i < 4; ++i)
                *(f16x8*)&lds[dbase + i * 1024 + lane * 16] = zf;
        }
    }
    __syncthreads();

    // ---------- K loop: 9 taps x 2 cin-halves, fully unrolled
    const int wm = w >> 2;
    const int wn = (wm == 0) ? (w & 3) : (((w & 3) + 2) & 3);   // heavy waves spread
    const int lm = lane & 15;
    const int lg = lane >> 4;

    f32x4 acc[4][4];
#pragma unroll
    for (int mf = 0; mf < 4; ++mf)
#pragma unroll
        for (int nf = 0; nf < 4; ++nf) acc[mf][nf] = (f32x4)0.0f;

    // per-lane swizzled A offsets: tx = lm + d (+ mf*16), granule g = kk*4+lg,
    // slot = g ^ (tx&7)  (mf*16 doesn't affect tx&7)
    unsigned av[3][2];
#pragma unroll
    for (int d = 0; d < 3; ++d)
#pragma unroll
        for (int kk = 0; kk < 2; ++kk) {
            const int tx = lm + d;
            av[d][kk] = (unsigned)(tx * 128 +
                        (((kk * 4 + lg) ^ (tx & 7)) << 4));
        }

    const f16x8* wb = (const f16x8*)wt + (size_t)(wn * 4) * 64 + lane;

    if (wn == 2) {
        // ---- c-gate: 2-term (h * w_hi + h * w_lo)
        f16x8 bh[4], bl[4];
#pragma unroll
        for (int it = 0; it < 18; ++it) {
            const int tap = it >> 1, kk = it & 1;
#pragma unroll
            for (int nf = 0; nf < 4; ++nf) {
                bh[nf] = wb[(size_t)it * 2048 + nf * 64];
                bl[nf] = wb[(size_t)it * 2048 + 1024 + nf * 64];
            }
            const int ty = tap / 3;
            const int d  = tap - ty * 3;
            const unsigned abase = (unsigned)((wm + ty) * RS2) + av[d][kk];
            __builtin_amdgcn_s_setprio(1);
#pragma unroll
            for (int mf = 0; mf < 4; ++mf) {
                const f16x8 ah = *(const f16x8*)&lds[abase + mf * 2048];
#pragma unroll
                for (int nf = 0; nf < 4; ++nf)
                    acc[mf][nf] = MFMA(ah, bh[nf], acc[mf][nf]);
#pragma unroll
                for (int nf = 0; nf < 4; ++nf)
                    acc[mf][nf] = MFMA(ah, bl[nf], acc[mf][nf]);
            }
            __builtin_amdgcn_s_setprio(0);
        }
    } else {
        // ---- i/f/o gates: 1-term (h * w_hi)
        f16x8 bh[4];
#pragma unroll
        for (int it = 0; it < 18; ++it) {
            const int tap = it >> 1, kk = it & 1;
#pragma unroll
            for (int nf = 0; nf < 4; ++nf)
                bh[nf] = wb[(size_t)it * 2048 + nf * 64];
            const int ty = tap / 3;
            const int d  = tap - ty * 3;
            const unsigned abase = (unsigned)((wm + ty) * RS2) + av[d][kk];
            __builtin_amdgcn_s_setprio(1);
#pragma unroll
            for (int mf = 0; mf < 4; ++mf) {
                const f16x8 ah = *(const f16x8*)&lds[abase + mf * 2048];
#pragma unroll
                for (int nf = 0; nf < 4; ++nf)
                    acc[mf][nf] = MFMA(ah, bh[nf], acc[mf][nf]);
            }
            __builtin_amdgcn_s_setprio(0);
        }
    }

    __syncthreads();

    // ---------- epilogue: z-exchange through LDS, fused LSTM pointwise
    float* zbuf = (float*)lds;
    const int f = tid & 63;
    const float bi = bias[f], bfv = bias[64 + f], bcv = bias[128 + f], bov = bias[192 + f];

#pragma unroll 1
    for (int half = 0; half < 2; ++half) {
        if (wm == half) {
#pragma unroll
            for (int mf = 0; mf < 4; ++mf)
#pragma unroll
                for (int nf = 0; nf < 4; ++nf)
#pragma unroll
                    for (int j = 0; j < 4; ++j)
                        zbuf[(mf * 16 + lg * 4 + j) * ZS + wn * 64 + nf * 16 + lm] =
                            acc[mf][nf][j];
        }
        __syncthreads();
        const int gy = y0 + half;
#pragma unroll 1
        for (int k2 = 0; k2 < 8; ++k2) {
            const int x = (tid >> 6) + k2 * 8;          // 0..63 (wave-uniform)
            const float* zz = zbuf + x * ZS;
            float zi  = zz[f]       + bi;
            float zfv = zz[64 + f]  + bfv;
            float zc  = zz[128 + f] + bcv;
            float zo  = zz[192 + f] + bov;
            size_t goff = (((size_t)bb * NH + gy) * NW + x) * NF + f;
            float cp = cprev[goff];
            float ig = hsig(zi), fg = hsig(zfv), og = hsig(zo);
            float cn = fg * cp + ig * ftanh(zc);
            cnew[goff] = cn;
            float hn = og * ftanh(cn);
            hout[(size_t)bb * OUT_BSTRIDE + (((size_t)gy * NW + x) * NF + f)] = hn;
            h2out[goff] = (f16)hn;                      // plain f16 h
        }
        __syncthreads();
    }
}

extern "C" void kernel_launch(void* const* d_in, const int* in_sizes, int n_in,
                              void* d_out, int out_size, void* d_ws, size_t ws_size,
                              hipStream_t stream) {
    const float* h0    = (const float*)d_in[1];
    const float* c0    = (const float*)d_in[2];
    const float* kern  = (const float*)d_in[3];
    const float* rkern = (const float*)d_in[4];
    const float* bias  = (const float*)d_in[5];
    float* out = (float*)d_out;

    f16* wf2 = (f16*)d_ws;                                    // 9.4 MB
    f16* h2a = wf2 + (size_t)NT * WSTEP * 8;                  // 8.4 MB (f16 h)
    f16* h2b = h2a + (size_t)NB * HWF;                        // 8.4 MB
    float* cbuf = (float*)(h2b + (size_t)NB * HWF);           // 16.8 MB

    fuse_split_w<<<(NT * 9 * NG * 8 + 255) / 256, 256, 0, stream>>>(kern, rkern, wf2);
    split_h<<<((int)(NB * HWF) + 255) / 256, 256, 0, stream>>>(h0, h2a);

    dim3 grid(NH / 2, NB);
    for (int t = 0; t < NT; ++t) {
        const f16* hin = (t & 1) ? h2b : h2a;
        f16* hnx       = (t & 1) ? h2a : h2b;
        convlstm_mfma_step<<<grid, 512, 0, stream>>>(
            hin, hnx,
            (t == 0) ? c0 : cbuf, cbuf,
            out + (size_t)t * HWF,
            wf2 + (size_t)t * WSTEP * 8,
            bias + t * NG);
    }
}

// Round 11
// 468.226 us; speedup vs baseline: 11.1678x; 1.1932x over previous
//
#include <hip/hip_runtime.h>
#include <math.h>

typedef _Float16 f16;
typedef _Float16 f16x4 __attribute__((ext_vector_type(4)));
typedef _Float16 f16x8 __attribute__((ext_vector_type(8)));
typedef float f32x4 __attribute__((ext_vector_type(4)));

#define NB 16      // batch
#define NT 16      // time steps
#define NH 64
#define NW 64
#define NF 64      // features
#define NG 256     // 4*F
#define HWF ((size_t)NH * NW * NF)          // 262144
#define OUT_BSTRIDE ((size_t)NT * HWF)      // d_out batch stride
#define RS2 8448                            // LDS row stride = 66 * 128 B (x-padded, f16 h)
#define ZS 258                              // zbuf row stride in floats
#define WSTEP ((size_t)18432)               // per-step wf2 size in f16x8 chunks (hi-only)

#define MFMA(a, b, c) __builtin_amdgcn_mfma_f32_16x16x32_f16((a), (b), (c), 0, 0, 0)

__device__ __forceinline__ void gload_lds16(const void* g, void* l) {
    __builtin_amdgcn_global_load_lds(
        (const __attribute__((address_space(1))) unsigned int*)(g),
        (__attribute__((address_space(3))) unsigned int*)(l), 16, 0, 0);
}

__device__ __forceinline__ float hsig(float x) {
    return fminf(fmaxf(0.2f * x + 0.5f, 0.0f), 1.0f);
}

// fast tanh via v_exp_f32 (rounds 8-10 verified absmax-neutral)
__device__ __forceinline__ float ftanh(float x) {
    float t = __builtin_amdgcn_exp2f(x * 2.885390081777927f);
    return 1.0f - 2.0f * __builtin_amdgcn_rcpf(t + 1.0f);
}

// ---- prologue 1: fuse W+U -> f16 (hi only), lane-ordered chunks:
// chunk (f16x8 units): (tap*2+kk)*1024 + (cout>>4)*64 + lane
// lane = lg*16 + (cout&15) holds cin = kk*32 + lg*8 .. +7.
__global__ void fuse_w_hi(const float* __restrict__ k, const float* __restrict__ rk,
                          f16* __restrict__ wf2) {
    int idx = blockIdx.x * 256 + threadIdx.x;      // over 16*9*256*8 = 294912
    if (idx >= NT * 9 * NG * 8) return;
    int g8   = idx & 7;
    int cout = (idx >> 3) & 255;
    int tt   = idx >> 11;          // t*9 + tap
    int tap  = tt % 9;
    int t    = tt / 9;
    int kk = g8 >> 2, lg = g8 & 3;

    const float* ks = k  + (size_t)tt * NF * NG + cout;
    const float* rs = rk + (size_t)tt * NF * NG + cout;

    f16 hi8[8];
#pragma unroll
    for (int j = 0; j < 8; ++j) {
        int cin = kk * 32 + lg * 8 + j;
        hi8[j] = (f16)(ks[(size_t)cin * NG] + rs[(size_t)cin * NG]);
    }
    const int lane = lg * 16 + (cout & 15);
    size_t chunk = (size_t)t * WSTEP + (size_t)(tap * 2 + kk) * 1024 +
                   (size_t)(cout >> 4) * 64 + lane;
    *(f16x8*)&wf2[chunk * 8] = *(f16x8*)hi8;
}

// ---- prologue 2: f32 -> f16 vectorized converter (h0 and c0)
__global__ void f32_to_f16(const float* __restrict__ src, f16* __restrict__ dst, int n4) {
    int i = blockIdx.x * 256 + threadIdx.x;
    if (i >= n4) return;
    float4 v = ((const float4*)src)[i];
    f16x4 o = { (f16)v.x, (f16)v.y, (f16)v.z, (f16)v.w };
    *(f16x4*)&dst[(size_t)i * 4] = o;
}

// ---- one ConvLSTM step: uniform 1-term f16 conv for all 4 gates.
// 8 waves (2m x 4n); block tile 128 positions x 256 couts; c state in f16.
// h tile f16: [4 rows][tx 0..65][8 granules of 16B], slot = g ^ (tx&7).
__global__ void __launch_bounds__(512, 4)
convlstm_mfma_step(const f16* __restrict__ h2in, f16* __restrict__ h2out,
                   f16* __restrict__ cbuf,        // f16 cell state (in-place)
                   float* __restrict__ hout,        // d_out + t*HWF
                   const f16* __restrict__ wt,      // hi-only lane-ordered chunks
                   const float* __restrict__ bias)  // [256] for this t
{
    __shared__ __align__(16) unsigned char lds[67584];

    const int tid  = threadIdx.x;
    const int w    = tid >> 6;
    const int lane = tid & 63;
    const int bb   = blockIdx.y;
    const int y0   = blockIdx.x * 2;

    // zero the pad columns tx=0 and tx=65 (4 rows x 2 x 128B)
    if (tid < 64) {
        int row = tid >> 4, side = (tid >> 3) & 1, j = tid & 7;
        *(f16x8*)&lds[row * RS2 + side * (65 * 128) + j * 16] = (f16x8)(_Float16)0.0f;
    }

    // stage rows y0-1 .. y0+2 (f16, 128B per (y,x)); pre-swizzled global source
    {
        const int r    = w >> 1;               // tile row 0..3
        const int gy   = y0 - 1 + r;
        const int half = w & 1;
        const unsigned dbase = r * RS2 + 128 + half * 4096;  // wave-uniform
        if (gy >= 0 && gy < NH) {
            const unsigned char* gsrc = (const unsigned char*)h2in +
                ((((size_t)bb * NH + gy) * NW) << 7);        // 128 B per (y,x)
#pragma unroll
            for (int i = 0; i < 4; ++i) {
                const int xrel = half * 32 + i * 8 + (lane >> 3);
                const unsigned src = ((unsigned)xrel << 7) +
                    ((unsigned)((lane & 7) ^ ((xrel + 1) & 7)) << 4);
                gload_lds16(gsrc + src, (void*)&lds[dbase + i * 1024]);
            }
        } else {
            const f16x8 zf = (f16x8)(_Float16)0.0f;
#pragma unroll
            for (int i = 0; i < 4; ++i)
                *(f16x8*)&lds[dbase + i * 1024 + lane * 16] = zf;
        }
    }
    __syncthreads();

    // ---------- K loop: 9 taps x 2 cin-halves, fully unrolled, 1-term f16
    const int wm = w >> 2;
    const int wn = w & 3;
    const int lm = lane & 15;
    const int lg = lane >> 4;

    f32x4 acc[4][4];
#pragma unroll
    for (int mf = 0; mf < 4; ++mf)
#pragma unroll
        for (int nf = 0; nf < 4; ++nf) acc[mf][nf] = (f32x4)0.0f;

    // per-lane swizzled A offsets: tx = lm + d, granule g = kk*4+lg, slot = g ^ (tx&7)
    unsigned av[3][2];
#pragma unroll
    for (int d = 0; d < 3; ++d)
#pragma unroll
        for (int kk = 0; kk < 2; ++kk) {
            const int tx = lm + d;
            av[d][kk] = (unsigned)(tx * 128 +
                        (((kk * 4 + lg) ^ (tx & 7)) << 4));
        }

    const f16x8* wb = (const f16x8*)wt + (size_t)(wn * 4) * 64 + lane;

    f16x8 bh[4];
#pragma unroll
    for (int it = 0; it < 18; ++it) {
        const int tap = it >> 1, kk = it & 1;
#pragma unroll
        for (int nf = 0; nf < 4; ++nf)
            bh[nf] = wb[(size_t)it * 1024 + nf * 64];
        const int ty = tap / 3;
        const int d  = tap - ty * 3;
        const unsigned abase = (unsigned)((wm + ty) * RS2) + av[d][kk];
        __builtin_amdgcn_s_setprio(1);
#pragma unroll
        for (int mf = 0; mf < 4; ++mf) {
            const f16x8 ah = *(const f16x8*)&lds[abase + mf * 2048];
#pragma unroll
            for (int nf = 0; nf < 4; ++nf)
                acc[mf][nf] = MFMA(ah, bh[nf], acc[mf][nf]);
        }
        __builtin_amdgcn_s_setprio(0);
    }

    __syncthreads();

    // ---------- epilogue: z-exchange through LDS, fused LSTM pointwise (c in f16)
    float* zbuf = (float*)lds;
    const int f = tid & 63;
    const float bi = bias[f], bfv = bias[64 + f], bcv = bias[128 + f], bov = bias[192 + f];

#pragma unroll 1
    for (int half = 0; half < 2; ++half) {
        if (wm == half) {
#pragma unroll
            for (int mf = 0; mf < 4; ++mf)
#pragma unroll
                for (int nf = 0; nf < 4; ++nf)
#pragma unroll
                    for (int j = 0; j < 4; ++j)
                        zbuf[(mf * 16 + lg * 4 + j) * ZS + wn * 64 + nf * 16 + lm] =
                            acc[mf][nf][j];
        }
        __syncthreads();
        const int gy = y0 + half;
#pragma unroll 1
        for (int k2 = 0; k2 < 8; ++k2) {
            const int x = (tid >> 6) + k2 * 8;          // 0..63 (wave-uniform)
            const float* zz = zbuf + x * ZS;
            float zi  = zz[f]       + bi;
            float zfv = zz[64 + f]  + bfv;
            float zc  = zz[128 + f] + bcv;
            float zo  = zz[192 + f] + bov;
            size_t goff = (((size_t)bb * NH + gy) * NW + x) * NF + f;
            float cp = (float)cbuf[goff];
            float ig = hsig(zi), fg = hsig(zfv), og = hsig(zo);
            float cn = fg * cp + ig * ftanh(zc);
            cbuf[goff] = (f16)cn;
            float hn = og * ftanh(cn);
            hout[(size_t)bb * OUT_BSTRIDE + (((size_t)gy * NW + x) * NF + f)] = hn;
            h2out[goff] = (f16)hn;
        }
        __syncthreads();
    }
}

extern "C" void kernel_launch(void* const* d_in, const int* in_sizes, int n_in,
                              void* d_out, int out_size, void* d_ws, size_t ws_size,
                              hipStream_t stream) {
    const float* h0    = (const float*)d_in[1];
    const float* c0    = (const float*)d_in[2];
    const float* kern  = (const float*)d_in[3];
    const float* rkern = (const float*)d_in[4];
    const float* bias  = (const float*)d_in[5];
    float* out = (float*)d_out;

    f16* wf2   = (f16*)d_ws;                                  // 4.7 MB (hi only)
    f16* h2a   = wf2 + (size_t)NT * WSTEP * 8;                // 8.4 MB
    f16* h2b   = h2a + (size_t)NB * HWF;                      // 8.4 MB
    f16* cbuf  = h2b + (size_t)NB * HWF;                      // 8.4 MB (f16 c state)

    const int n4 = (int)(NB * HWF / 4);                       // 1,048,576
    fuse_w_hi<<<(NT * 9 * NG * 8 + 255) / 256, 256, 0, stream>>>(kern, rkern, wf2);
    f32_to_f16<<<(n4 + 255) / 256, 256, 0, stream>>>(h0, h2a, n4);
    f32_to_f16<<<(n4 + 255) / 256, 256, 0, stream>>>(c0, cbuf, n4);

    dim3 grid(NH / 2, NB);
    for (int t = 0; t < NT; ++t) {
        const f16* hin = (t & 1) ? h2b : h2a;
        f16* hnx       = (t & 1) ? h2a : h2b;
        convlstm_mfma_step<<<grid, 512, 0, stream>>>(
            hin, hnx, cbuf,
            out + (size_t)t * HWF,
            wf2 + (size_t)t * WSTEP * 8,
            bias + t * NG);
    }
}